// Round 1
// baseline (1250.303 us; speedup 1.0000x reference)
//
#include <hip/hip_runtime.h>
#include <hip/hip_bf16.h>

#define HH 512
#define WW 512
#define HWSZ (512 * 512)
#define CIN 64
#define MID 32

#define TS 16
#define HC 18            // TS + 2 halo
#define NCOL (HC * HC)   // 324 staging columns
#define X1STRIDE 17      // 16 bf16x2 words + 1 pad word -> conflict-free

__device__ __forceinline__ unsigned f2bf(float v) {
    unsigned u = __float_as_uint(v);
    return (u + 0x7fffu + ((u >> 16) & 1u)) >> 16;  // round-to-nearest-even bf16
}

__global__ __launch_bounds__(256, 2)
void fused_local_attn(const float* __restrict__ x,
                      const float* __restrict__ w1, const float* __restrict__ b1,
                      const float* __restrict__ w2, const float* __restrict__ b2,
                      const float* __restrict__ w3, const float* __restrict__ b3,
                      const float* __restrict__ gamma,
                      float* __restrict__ out)
{
    __shared__ unsigned sX1[NCOL * X1STRIDE];  // 22032 B, x1 tile+halo in bf16 pairs

    const int tid = threadIdx.x;
    const int lx = tid & 15, ly = tid >> 4;
    const int b  = blockIdx.z;
    const int w0 = blockIdx.x * TS, h0 = blockIdx.y * TS;
    const int hh = h0 + ly, ww = w0 + lx;

    const float* xb = x + (size_t)b * CIN * HWSZ;

    // ---- Stage x1 = w1.x + b1 for tile+halo into LDS (bf16) ----
    for (int cidx = tid; cidx < NCOL; cidx += 256) {
        int sy = cidx / HC;
        int sx = cidx - sy * HC;
        int gh = h0 - 1 + sy, gw = w0 - 1 + sx;
        bool valid = (gh >= 0) && (gh < HH) && (gw >= 0) && (gw < WW);
        float acc[MID];
#pragma unroll
        for (int oc = 0; oc < MID; ++oc) acc[oc] = valid ? b1[oc] : 0.f;
        if (valid) {
            const float* xp = xb + gh * WW + gw;
#pragma unroll 4
            for (int ic = 0; ic < CIN; ++ic) {
                float xv = xp[(size_t)ic * HWSZ];
#pragma unroll
                for (int oc = 0; oc < MID; ++oc) acc[oc] += w1[oc * CIN + ic] * xv;
            }
        }
#pragma unroll
        for (int p = 0; p < MID / 2; ++p)
            sX1[cidx * X1STRIDE + p] = f2bf(acc[2 * p]) | (f2bf(acc[2 * p + 1]) << 16);
    }
    __syncthreads();

    // ---- x2 for own pixel (pre-scaled by -log2(e) for exp2-based sigmoid) ----
    float x2n[MID];
#pragma unroll
    for (int oc = 0; oc < MID; ++oc) x2n[oc] = b2[oc];
    {
        const float* xp = xb + hh * WW + ww;
#pragma unroll 4
        for (int ic = 0; ic < CIN; ++ic) {
            float xv = xp[(size_t)ic * HWSZ];
#pragma unroll
            for (int oc = 0; oc < MID; ++oc) x2n[oc] += w2[oc * CIN + ic] * xv;
        }
    }
#pragma unroll
    for (int oc = 0; oc < MID; ++oc) x2n[oc] *= -1.4426950408889634f;

    // ---- S[9]: attention weights vs the 9 neighbors; 0 for OOB neighbors ----
    float S[9];
    float T = 0.f;
#pragma unroll
    for (int dy = 0; dy < 3; ++dy) {
#pragma unroll
        for (int dx = 0; dx < 3; ++dx) {
            int j = dy * 3 + dx;
            int gh = hh - 1 + dy, gw = ww - 1 + dx;
            float s = 0.f;
            if ((gh >= 0) && (gh < HH) && (gw >= 0) && (gw < WW)) {
                int col = (ly + dy) * HC + (lx + dx);
                const unsigned* xp1 = &sX1[col * X1STRIDE];
#pragma unroll
                for (int p = 0; p < MID / 2; ++p) {
                    unsigned u = xp1[p];
                    float lo = __uint_as_float(u << 16);
                    float hi = __uint_as_float(u & 0xffff0000u);
                    float t0 = x2n[2 * p] * lo;       // = -log2e * x2 * x1s
                    float t1 = x2n[2 * p + 1] * hi;
                    s += __builtin_amdgcn_rcpf(1.f + exp2f(t0));  // sigmoid
                    s += __builtin_amdgcn_rcpf(1.f + exp2f(t1));
                }
            }
            S[j] = s;
            T += s;
        }
    }

    // ---- y[ic] = sum_q S(p,q) * x[ic,q]  (clamped coords; S=0 nullifies OOB) ----
    int off[9];
#pragma unroll
    for (int dy = 0; dy < 3; ++dy) {
        int gh = hh - 1 + dy;
        gh = gh < 0 ? 0 : (gh > HH - 1 ? HH - 1 : gh);
#pragma unroll
        for (int dx = 0; dx < 3; ++dx) {
            int gw = ww - 1 + dx;
            gw = gw < 0 ? 0 : (gw > WW - 1 ? WW - 1 : gw);
            off[dy * 3 + dx] = gh * WW + gw;
        }
    }
    float y[CIN];
#pragma unroll 8
    for (int ic = 0; ic < CIN; ++ic) {
        const float* xp = xb + (size_t)ic * HWSZ;
        float a = 0.f;
#pragma unroll
        for (int j = 0; j < 9; ++j) a += S[j] * xp[off[j]];
        y[ic] = a;
    }

    // ---- epilogue: out[c] = x[c] + g * (w3[c,:].y + b3[c]*T) ----
    const float g = gamma[0];
    const float* xp = xb + hh * WW + ww;
    float* op = out + (size_t)b * CIN * HWSZ + hh * WW + ww;
#pragma unroll 2
    for (int c = 0; c < CIN; ++c) {
        float acc = b3[c] * T;
#pragma unroll
        for (int ic = 0; ic < CIN; ++ic) acc += w3[c * CIN + ic] * y[ic];
        op[(size_t)c * HWSZ] = xp[(size_t)c * HWSZ] + g * acc;
    }
}

extern "C" void kernel_launch(void* const* d_in, const int* in_sizes, int n_in,
                              void* d_out, int out_size, void* d_ws, size_t ws_size,
                              hipStream_t stream) {
    const float* x     = (const float*)d_in[0];
    const float* w1    = (const float*)d_in[1];
    const float* b1    = (const float*)d_in[2];
    const float* w2    = (const float*)d_in[3];
    const float* b2    = (const float*)d_in[4];
    const float* w3    = (const float*)d_in[5];
    const float* b3    = (const float*)d_in[6];
    const float* gamma = (const float*)d_in[7];
    float* out = (float*)d_out;

    dim3 grid(WW / TS, HH / TS, 4);
    fused_local_attn<<<grid, dim3(256), 0, stream>>>(x, w1, b1, w2, b2, w3, b3, gamma, out);
}